// Round 19
// baseline (47.537 us; speedup 1.0000x reference)
//
#include <hip/hip_runtime.h>
#include <stdint.h>

#define IMG  512
#define CPT  8
#define CGRP (IMG / CPT)    // 64 col-groups per row
#define BLK  1024

typedef _Float16 h2    __attribute__((ext_vector_type(2)));
typedef __fp16   f16x2 __attribute__((ext_vector_type(2)));

static __device__ __forceinline__ h2 pkrtz(float a, float b) {
    f16x2 t = __builtin_amdgcn_cvt_pkrtz(a, b);   // v_cvt_pkrtz_f16_f32
    return __builtin_bit_cast(h2, t);
}

#if __has_builtin(__builtin_amdgcn_fdot2)
#define FDOT2(a, b, c) __builtin_amdgcn_fdot2((a), (b), (c), false)
#else
static __device__ __forceinline__ float fdot2_sw(h2 a, h2 b, float c) {
    return fmaf((float)a.x, (float)b.x, fmaf((float)a.y, (float)b.y, c));
}
#define FDOT2(a, b, c) fdot2_sw((a), (b), (c))
#endif

// R18 body (34.7us) with launch-geometry change: 1024-thread blocks,
// __launch_bounds__(1024,2) -> 2 blocks/CU co-resident = 32 waves/CU (100%
// occupancy; VGPR 60 <= 64 cap). R17/R18 showed +-10% VALU issue moves wall
// <1% -- each wave's conv->ds_read->tap chain is ~40% duty, so co-resident
// wave count is the remaining lever. Also 4x less total LUT-fill work.

__global__ __launch_bounds__(BLK, 2) void fused_convtap_kernel(
    const float* __restrict__ x,   // (B,1,512,512)
    const float* __restrict__ W,   // (9,1,3,3)
    const float* __restrict__ Bv,  // (9,)
    float* __restrict__ out)       // (B,1,512,512)
{
    __shared__ float lut[2048];

    const int tid = blockIdx.x * BLK + threadIdx.x;
    const int xg  = tid & (CGRP - 1);
    const int row = tid >> 6;            // b*IMG + y
    const int y   = row & (IMG - 1);
    const int x0  = xg * CPT;

    const float* xr = x + (size_t)row * IMG;
    const bool has_l = (x0 > 0);
    const bool has_r = (x0 < IMG - CPT);

    // ---- issue global row loads FIRST (latency hides under LUT fill) ----
    float r0[10], r1[10], r2[10];
    {
        auto load_row = [&](const float* p, float (&r)[10]) {
            float4 a = *reinterpret_cast<const float4*>(p + x0);
            float4 c = *reinterpret_cast<const float4*>(p + x0 + 4);
            r[1] = a.x; r[2] = a.y; r[3] = a.z; r[4] = a.w;
            r[5] = c.x; r[6] = c.y; r[7] = c.z; r[8] = c.w;
            r[0] = has_l ? p[x0 - 1] : 0.0f;
            r[9] = has_r ? p[x0 + 8] : 0.0f;
        };
        auto zero_row = [&](float (&r)[10]) {
#pragma unroll
            for (int k = 0; k < 10; ++k) r[k] = 0.0f;
        };
        if (y > 0)       load_row(xr - IMG, r0); else zero_row(r0);
                         load_row(xr,       r1);
        if (y < IMG - 1) load_row(xr + IMG, r2); else zero_row(r2);
    }

    // ---- LUT fill: entry i = tanh((i+0.5)/256 - 4); 2 entries/thread ----
    {
        const float E8 = 2980.9579870417283f;   // e^8 (x-step of 4.0)
        const float xi0 = fmaf((float)threadIdx.x, 0.00390625f,
                               0.001953125f - 4.0f);
        float e = __builtin_amdgcn_exp2f(xi0 * 2.8853900817779268f);
        lut[threadIdx.x]        = 1.0f - 2.0f * __builtin_amdgcn_rcpf(e + 1.0f);
        e *= E8;
        lut[threadIdx.x + 1024] = 1.0f - 2.0f * __builtin_amdgcn_rcpf(e + 1.0f);
    }
    __syncthreads();

    // Uniform weights scaled by 1024 (exact); bias*1024 + 4096.
    h2 u[9][4];
    float w8[9], bv[9];
#pragma unroll
    for (int c = 0; c < 9; ++c) {
#pragma unroll
        for (int k = 0; k < 4; ++k)
            u[c][k] = pkrtz(W[c * 9 + 2 * k] * 1024.0f,
                            W[c * 9 + 2 * k + 1] * 1024.0f);
        w8[c] = W[c * 9 + 8] * 1024.0f;
        bv[c] = fmaf(Bv[c], 1024.0f, 4096.0f);
    }

    // tanh lookup from byte-index accumulator: med3 + cvt + and + ds_read.
    const char* lutb = (const char*)lut;
    auto tlu = [&](float v) -> float {
        float t = __builtin_amdgcn_fmed3f(v, 0.0f, 8188.0f);
        int   i = ((int)t) & ~3;
        return *(const float*)(lutb + i);
    };

    float o[CPT];
#pragma unroll
    for (int tp = 0; tp < 4; ++tp) {
        const int t0 = 2 * tp;
        // f16 K-pairs for pixels t0/t0+1:
        // A=(p0q0,p0q1) B=(p0q2,p1q0) C=(p1q1,p1q2) D=(p2q0,p2q1), lone p2q2 f32
        h2 A0 = pkrtz(r0[t0],     r0[t0 + 1]);
        h2 B0 = pkrtz(r0[t0 + 2], r1[t0]);
        h2 C0 = pkrtz(r1[t0 + 1], r1[t0 + 2]);
        h2 D0 = pkrtz(r2[t0],     r2[t0 + 1]);
        h2 A1 = pkrtz(r0[t0 + 1], r0[t0 + 2]);
        h2 B1 = pkrtz(r0[t0 + 3], r1[t0 + 1]);
        h2 C1 = pkrtz(r1[t0 + 2], r1[t0 + 3]);
        h2 D1 = pkrtz(r2[t0 + 1], r2[t0 + 2]);

        float ox = 0.0f, oy = 0.0f;
#pragma unroll
        for (int c = 0; c < 9; ++c) {
            float fx = bv[c], fy = bv[c];
            fx = FDOT2(A0, u[c][0], fx);
            fy = FDOT2(A1, u[c][0], fy);
            fx = FDOT2(B0, u[c][1], fx);
            fy = FDOT2(B1, u[c][1], fy);
            fx = FDOT2(C0, u[c][2], fx);
            fy = FDOT2(C1, u[c][2], fy);
            fx = FDOT2(D0, u[c][3], fx);
            fy = FDOT2(D1, u[c][3], fy);
            fx = fmaf(r2[t0 + 2], w8[c], fx);
            fy = fmaf(r2[t0 + 3], w8[c], fy);

            const float thx = tlu(fx);
            const float thy = tlu(fy);

            // tap stage: out += patch[j][i] * tanh(fc_c), c = 3i+j
            const int i = c / 3, j = c - 3 * i;
            const float* rj = (j == 0) ? r0 : (j == 1) ? r1 : r2;
            ox = fmaf(rj[t0 + i],     thx, ox);
            oy = fmaf(rj[t0 + 1 + i], thy, oy);
        }
        o[t0] = ox; o[t0 + 1] = oy;
    }

    float* orow = out + (size_t)row * IMG + x0;
    *reinterpret_cast<float4*>(orow)     = make_float4(o[0], o[1], o[2], o[3]);
    *reinterpret_cast<float4*>(orow + 4) = make_float4(o[4], o[5], o[6], o[7]);
}

extern "C" void kernel_launch(void* const* d_in, const int* in_sizes, int n_in,
                              void* d_out, int out_size, void* d_ws, size_t ws_size,
                              hipStream_t stream) {
    const float* x  = (const float*)d_in[0];   // (B,1,512,512) f32
    const float* W  = (const float*)d_in[1];   // (9,1,3,3)     f32
    const float* Bv = (const float*)d_in[2];   // (9,)          f32
    float* out = (float*)d_out;

    const int batch   = in_sizes[0] / (IMG * IMG);   // 32
    const int threads = batch * IMG * CGRP;          // 1,048,576
    const int grid    = threads / BLK;               // 1024
    fused_convtap_kernel<<<grid, BLK, 0, stream>>>(x, W, Bv, out);
}

// Round 20
// 38.627 us; speedup vs baseline: 1.2306x; 1.2306x over previous
//
#include <hip/hip_runtime.h>
#include <stdint.h>

#define IMG  512
#define CPT  4
#define CGRP (IMG / CPT)    // 128 col-groups per row

typedef _Float16 h2    __attribute__((ext_vector_type(2)));
typedef __fp16   f16x2 __attribute__((ext_vector_type(2)));

static __device__ __forceinline__ h2 pkrtz(float a, float b) {
    f16x2 t = __builtin_amdgcn_cvt_pkrtz(a, b);   // v_cvt_pkrtz_f16_f32
    return __builtin_bit_cast(h2, t);
}

#if __has_builtin(__builtin_amdgcn_fdot2)
#define FDOT2(a, b, c) __builtin_amdgcn_fdot2((a), (b), (c), false)
#else
static __device__ __forceinline__ float fdot2_sw(h2 a, h2 b, float c) {
    return fmaf((float)a.x, (float)b.x, fmaf((float)a.y, (float)b.y, c));
}
#define FDOT2(a, b, c) fdot2_sw((a), (b), (c))
#endif

// R18 body (34.7us best) at CPT=4: 2x waves (32768), ~half per-thread serial
// work, lower VGPR. R16/R19 showed fatter threads/blocks lose; this probes
// the thin end. Everything else identical: dot2 conv + byte-index LDS LUT
// (weights pre-scaled by 1024 exact, bias*1024+4096).

__global__ __launch_bounds__(256) void fused_convtap_kernel(
    const float* __restrict__ x,   // (B,1,512,512)
    const float* __restrict__ W,   // (9,1,3,3)
    const float* __restrict__ Bv,  // (9,)
    float* __restrict__ out)       // (B,1,512,512)
{
    __shared__ float lut[2048];

    const int tid = blockIdx.x * 256 + threadIdx.x;
    const int xg  = tid & (CGRP - 1);
    const int row = tid >> 7;            // b*IMG + y
    const int y   = row & (IMG - 1);
    const int x0  = xg * CPT;

    const float* xr = x + (size_t)row * IMG;
    const bool has_l = (x0 > 0);
    const bool has_r = (x0 < IMG - CPT);

    // ---- issue global row loads FIRST (latency hides under LUT fill) ----
    // cols x0-1 .. x0+4 (6 values/row), zero-padded outside.
    float r0[6], r1[6], r2[6];
    {
        auto load_row = [&](const float* p, float (&r)[6]) {
            float4 a = *reinterpret_cast<const float4*>(p + x0);
            r[1] = a.x; r[2] = a.y; r[3] = a.z; r[4] = a.w;
            r[0] = has_l ? p[x0 - 1] : 0.0f;
            r[5] = has_r ? p[x0 + 4] : 0.0f;
        };
        auto zero_row = [&](float (&r)[6]) {
#pragma unroll
            for (int k = 0; k < 6; ++k) r[k] = 0.0f;
        };
        if (y > 0)       load_row(xr - IMG, r0); else zero_row(r0);
                         load_row(xr,       r1);
        if (y < IMG - 1) load_row(xr + IMG, r2); else zero_row(r2);
    }

    // ---- geometric LUT fill: entry i = tanh((i+0.5)/256 - 4) ----
    {
        const float E2 = 7.38905609893065f;   // e^2 per x-step of 1.0
        const float xi0 = fmaf((float)threadIdx.x, 0.00390625f,
                               0.001953125f - 4.0f);
        float e = __builtin_amdgcn_exp2f(xi0 * 2.8853900817779268f);
#pragma unroll
        for (int k = 0; k < 8; ++k) {
            lut[threadIdx.x + (k << 8)] =
                1.0f - 2.0f * __builtin_amdgcn_rcpf(e + 1.0f);
            e *= E2;
        }
    }
    __syncthreads();

    // Uniform weights scaled by 1024 (exact); bias*1024 + 4096.
    h2 u[9][4];
    float w8[9], bv[9];
#pragma unroll
    for (int c = 0; c < 9; ++c) {
#pragma unroll
        for (int k = 0; k < 4; ++k)
            u[c][k] = pkrtz(W[c * 9 + 2 * k] * 1024.0f,
                            W[c * 9 + 2 * k + 1] * 1024.0f);
        w8[c] = W[c * 9 + 8] * 1024.0f;
        bv[c] = fmaf(Bv[c], 1024.0f, 4096.0f);
    }

    // tanh lookup from byte-index accumulator: med3 + cvt + and + ds_read.
    const char* lutb = (const char*)lut;
    auto tlu = [&](float v) -> float {
        float t = __builtin_amdgcn_fmed3f(v, 0.0f, 8188.0f);
        int   i = ((int)t) & ~3;
        return *(const float*)(lutb + i);
    };

    float o[CPT];
#pragma unroll
    for (int tp = 0; tp < 2; ++tp) {
        const int t0 = 2 * tp;
        // f16 K-pairs for pixels t0/t0+1:
        // A=(p0q0,p0q1) B=(p0q2,p1q0) C=(p1q1,p1q2) D=(p2q0,p2q1), lone p2q2 f32
        h2 A0 = pkrtz(r0[t0],     r0[t0 + 1]);
        h2 B0 = pkrtz(r0[t0 + 2], r1[t0]);
        h2 C0 = pkrtz(r1[t0 + 1], r1[t0 + 2]);
        h2 D0 = pkrtz(r2[t0],     r2[t0 + 1]);
        h2 A1 = pkrtz(r0[t0 + 1], r0[t0 + 2]);
        h2 B1 = pkrtz(r0[t0 + 3], r1[t0 + 1]);
        h2 C1 = pkrtz(r1[t0 + 2], r1[t0 + 3]);
        h2 D1 = pkrtz(r2[t0 + 1], r2[t0 + 2]);

        float ox = 0.0f, oy = 0.0f;
#pragma unroll
        for (int c = 0; c < 9; ++c) {
            float fx = bv[c], fy = bv[c];
            fx = FDOT2(A0, u[c][0], fx);
            fy = FDOT2(A1, u[c][0], fy);
            fx = FDOT2(B0, u[c][1], fx);
            fy = FDOT2(B1, u[c][1], fy);
            fx = FDOT2(C0, u[c][2], fx);
            fy = FDOT2(C1, u[c][2], fy);
            fx = FDOT2(D0, u[c][3], fx);
            fy = FDOT2(D1, u[c][3], fy);
            fx = fmaf(r2[t0 + 2], w8[c], fx);
            fy = fmaf(r2[t0 + 3], w8[c], fy);

            const float thx = tlu(fx);
            const float thy = tlu(fy);

            // tap stage: out += patch[j][i] * tanh(fc_c), c = 3i+j
            const int i = c / 3, j = c - 3 * i;
            const float* rj = (j == 0) ? r0 : (j == 1) ? r1 : r2;
            ox = fmaf(rj[t0 + i],     thx, ox);
            oy = fmaf(rj[t0 + 1 + i], thy, oy);
        }
        o[t0] = ox; o[t0 + 1] = oy;
    }

    float* orow = out + (size_t)row * IMG + x0;
    *reinterpret_cast<float4*>(orow) = make_float4(o[0], o[1], o[2], o[3]);
}

extern "C" void kernel_launch(void* const* d_in, const int* in_sizes, int n_in,
                              void* d_out, int out_size, void* d_ws, size_t ws_size,
                              hipStream_t stream) {
    const float* x  = (const float*)d_in[0];   // (B,1,512,512) f32
    const float* W  = (const float*)d_in[1];   // (9,1,3,3)     f32
    const float* Bv = (const float*)d_in[2];   // (9,)          f32
    float* out = (float*)d_out;

    const int batch   = in_sizes[0] / (IMG * IMG);   // 32
    const int threads = batch * IMG * CGRP;          // 2,097,152
    const int grid    = threads / 256;               // 8192
    fused_convtap_kernel<<<grid, 256, 0, stream>>>(x, W, Bv, out);
}

// Round 21
// 34.750 us; speedup vs baseline: 1.3680x; 1.1116x over previous
//
#include <hip/hip_runtime.h>
#include <stdint.h>

#define IMG  512
#define CPT  8
#define CGRP (IMG / CPT)    // 64 col-groups per row

typedef _Float16 h2    __attribute__((ext_vector_type(2)));
typedef __fp16   f16x2 __attribute__((ext_vector_type(2)));

static __device__ __forceinline__ h2 pkrtz(float a, float b) {
    f16x2 t = __builtin_amdgcn_cvt_pkrtz(a, b);   // v_cvt_pkrtz_f16_f32
    return __builtin_bit_cast(h2, t);
}

#if __has_builtin(__builtin_amdgcn_fdot2)
#define FDOT2(a, b, c) __builtin_amdgcn_fdot2((a), (b), (c), false)
#else
static __device__ __forceinline__ float fdot2_sw(h2 a, h2 b, float c) {
    return fmaf((float)a.x, (float)b.x, fmaf((float)a.y, (float)b.y, c));
}
#define FDOT2(a, b, c) fdot2_sw((a), (b), (c))
#endif

// FINAL (plateau revert to R18, best measured: 34.67us).
// Structure: fused single-pass stencil; v_dot2_f32_f16 conv (weights exact-
// scaled by 1024 so the accumulator IS the LUT byte index); 2048-entry LDS
// tanh LUT (geometric fill: 1 exp2 + 7 mul + 8 rcp per thread); row loads
// issued before LUT fill to hide HBM latency; CPT=8, 256-thread blocks
// (granularity optimum per R16/R19/R20 sweeps).
// LUT: entry i = tanh((i+0.5)/256 - 4); byte idx = fc*1024 + 4096 clamped
// to [0, 8188] and floored to a multiple of 4. Total absmax 0.0625 (3.7x
// under threshold).

__global__ __launch_bounds__(256) void fused_convtap_kernel(
    const float* __restrict__ x,   // (B,1,512,512)
    const float* __restrict__ W,   // (9,1,3,3)
    const float* __restrict__ Bv,  // (9,)
    float* __restrict__ out)       // (B,1,512,512)
{
    __shared__ float lut[2048];

    const int tid = blockIdx.x * 256 + threadIdx.x;
    const int xg  = tid & (CGRP - 1);
    const int row = tid >> 6;            // b*IMG + y
    const int y   = row & (IMG - 1);
    const int x0  = xg * CPT;

    const float* xr = x + (size_t)row * IMG;
    const bool has_l = (x0 > 0);
    const bool has_r = (x0 < IMG - CPT);

    // ---- issue global row loads FIRST (latency hides under LUT fill) ----
    float r0[10], r1[10], r2[10];
    {
        auto load_row = [&](const float* p, float (&r)[10]) {
            float4 a = *reinterpret_cast<const float4*>(p + x0);
            float4 c = *reinterpret_cast<const float4*>(p + x0 + 4);
            r[1] = a.x; r[2] = a.y; r[3] = a.z; r[4] = a.w;
            r[5] = c.x; r[6] = c.y; r[7] = c.z; r[8] = c.w;
            r[0] = has_l ? p[x0 - 1] : 0.0f;
            r[9] = has_r ? p[x0 + 8] : 0.0f;
        };
        auto zero_row = [&](float (&r)[10]) {
#pragma unroll
            for (int k = 0; k < 10; ++k) r[k] = 0.0f;
        };
        if (y > 0)       load_row(xr - IMG, r0); else zero_row(r0);
                         load_row(xr,       r1);
        if (y < IMG - 1) load_row(xr + IMG, r2); else zero_row(r2);
    }

    // ---- geometric LUT fill: entry i = tanh((i+0.5)/256 - 4) ----
    {
        const float E2 = 7.38905609893065f;   // e^2 per x-step of 1.0
        const float xi0 = fmaf((float)threadIdx.x, 0.00390625f,
                               0.001953125f - 4.0f);
        float e = __builtin_amdgcn_exp2f(xi0 * 2.8853900817779268f);
#pragma unroll
        for (int k = 0; k < 8; ++k) {
            lut[threadIdx.x + (k << 8)] =
                1.0f - 2.0f * __builtin_amdgcn_rcpf(e + 1.0f);
            e *= E2;
        }
    }
    __syncthreads();

    // Uniform weights scaled by 1024 (exact); bias*1024 + 4096.
    h2 u[9][4];
    float w8[9], bv[9];
#pragma unroll
    for (int c = 0; c < 9; ++c) {
#pragma unroll
        for (int k = 0; k < 4; ++k)
            u[c][k] = pkrtz(W[c * 9 + 2 * k] * 1024.0f,
                            W[c * 9 + 2 * k + 1] * 1024.0f);
        w8[c] = W[c * 9 + 8] * 1024.0f;
        bv[c] = fmaf(Bv[c], 1024.0f, 4096.0f);
    }

    // tanh lookup from byte-index accumulator: med3 + cvt + and + ds_read.
    const char* lutb = (const char*)lut;
    auto tlu = [&](float v) -> float {
        float t = __builtin_amdgcn_fmed3f(v, 0.0f, 8188.0f);
        int   i = ((int)t) & ~3;
        return *(const float*)(lutb + i);
    };

    float o[CPT];
#pragma unroll
    for (int tp = 0; tp < 4; ++tp) {
        const int t0 = 2 * tp;
        // f16 K-pairs for pixels t0/t0+1:
        // A=(p0q0,p0q1) B=(p0q2,p1q0) C=(p1q1,p1q2) D=(p2q0,p2q1), lone p2q2 f32
        h2 A0 = pkrtz(r0[t0],     r0[t0 + 1]);
        h2 B0 = pkrtz(r0[t0 + 2], r1[t0]);
        h2 C0 = pkrtz(r1[t0 + 1], r1[t0 + 2]);
        h2 D0 = pkrtz(r2[t0],     r2[t0 + 1]);
        h2 A1 = pkrtz(r0[t0 + 1], r0[t0 + 2]);
        h2 B1 = pkrtz(r0[t0 + 3], r1[t0 + 1]);
        h2 C1 = pkrtz(r1[t0 + 2], r1[t0 + 3]);
        h2 D1 = pkrtz(r2[t0 + 1], r2[t0 + 2]);

        float ox = 0.0f, oy = 0.0f;
#pragma unroll
        for (int c = 0; c < 9; ++c) {
            float fx = bv[c], fy = bv[c];
            fx = FDOT2(A0, u[c][0], fx);
            fy = FDOT2(A1, u[c][0], fy);
            fx = FDOT2(B0, u[c][1], fx);
            fy = FDOT2(B1, u[c][1], fy);
            fx = FDOT2(C0, u[c][2], fx);
            fy = FDOT2(C1, u[c][2], fy);
            fx = FDOT2(D0, u[c][3], fx);
            fy = FDOT2(D1, u[c][3], fy);
            fx = fmaf(r2[t0 + 2], w8[c], fx);
            fy = fmaf(r2[t0 + 3], w8[c], fy);

            const float thx = tlu(fx);
            const float thy = tlu(fy);

            // tap stage: out += patch[j][i] * tanh(fc_c), c = 3i+j
            const int i = c / 3, j = c - 3 * i;
            const float* rj = (j == 0) ? r0 : (j == 1) ? r1 : r2;
            ox = fmaf(rj[t0 + i],     thx, ox);
            oy = fmaf(rj[t0 + 1 + i], thy, oy);
        }
        o[t0] = ox; o[t0 + 1] = oy;
    }

    float* orow = out + (size_t)row * IMG + x0;
    *reinterpret_cast<float4*>(orow)     = make_float4(o[0], o[1], o[2], o[3]);
    *reinterpret_cast<float4*>(orow + 4) = make_float4(o[4], o[5], o[6], o[7]);
}

extern "C" void kernel_launch(void* const* d_in, const int* in_sizes, int n_in,
                              void* d_out, int out_size, void* d_ws, size_t ws_size,
                              hipStream_t stream) {
    const float* x  = (const float*)d_in[0];   // (B,1,512,512) f32
    const float* W  = (const float*)d_in[1];   // (9,1,3,3)     f32
    const float* Bv = (const float*)d_in[2];   // (9,)          f32
    float* out = (float*)d_out;

    const int batch   = in_sizes[0] / (IMG * IMG);   // 32
    const int threads = batch * IMG * CGRP;          // 1,048,576
    const int grid    = threads / 256;               // 4096
    fused_convtap_kernel<<<grid, 256, 0, stream>>>(x, W, Bv, out);
}